// Round 5
// baseline (225.896 us; speedup 1.0000x reference)
//
#include <hip/hip_runtime.h>
#include <math.h>

// ---- compile-time physical constants (mirror the Python reference) ----
namespace k {
constexpr double dA     = 0.129907 + 0.095724;       // L_X + L_Y
constexpr double dR     = 4.0 * 0.0254;              // wheel radius
constexpr double dI     = 6.0;                       // inertia (== mass)
constexpr double dMOI   = 6.0 * (12.0 * 0.0254) * (12.0 * 0.0254) / 6.0;
constexpr float T_STALL   = (float)(5.4 / 100.0);
constexpr float INV_WFREE = (float)(1.0 / (1620.0 / 60.0 * 2.0 * 3.14159265358979323846));
constexpr float A         = (float)dA;
constexpr float INV_R     = (float)(1.0 / dR);
constexpr float INV_RI    = (float)(1.0 / (dR * dI));    // WT2LA rows 0,1 scale
constexpr float A_RMOI    = (float)(dA / (dR * dMOI));   // WT2LA row 2 scale
}

__device__ __forceinline__ float wheel_torque(float w, float m) {
    float p = m * w;
    // jnp.sign semantics: sign(0)=0 -> is_same_direction = 0.5
    float sgn = (float)(p > 0.0f) - (float)(p < 0.0f);
    float isd = 0.5f * (sgn + 1.0f);
    return k::T_STALL * (1.0f - fabsf(w) * isd * k::INV_WFREE) * m;
}

// One batch element. Native trig: v_sin_f32/v_cos_f32 (~3 instr each) instead
// of libm sincosf (~160 instr/pair was ~70% of all VALU work per R4 counters).
// |theta| ~ N(0,1) -> well inside native range; abs threshold 0.108 >> 1e-6.
__device__ __forceinline__ void mecanum_elem(const float st[6],
                                             float m0, float m1, float m2, float m3,
                                             float o[6]) {
    float theta = st[2];
    float s = __sinf(theta);
    float c = __cosf(theta);

    float v0 = st[3], v1 = st[4], v2 = st[5];

    // a2l = rot(cos(-t), sin(-t)) -> [[c, s, 0], [-s, c, 0], [0,0,1]]
    float lv0 = c * v0 + s * v1;
    float lv1 = c * v1 - s * v0;

    // wheel_vel = LV2WV @ local_vel; rows [1,-1,-A],[1,1,A],[1,1,-A],[1,-1,A], /R
    float al2 = k::A * v2;
    float w0 = (lv0 - lv1 - al2) * k::INV_R;
    float w1 = (lv0 + lv1 + al2) * k::INV_R;
    float w2 = (lv0 + lv1 - al2) * k::INV_R;
    float w3 = (lv0 - lv1 + al2) * k::INV_R;

    float t0 = wheel_torque(w0, m0);
    float t1 = wheel_torque(w1, m1);
    float t2 = wheel_torque(w2, m2);
    float t3 = wheel_torque(w3, m3);

    // local_accel = WT2LA @ torque
    float la0 = (t0 + t1 + t2 + t3) * k::INV_RI;
    float la1 = (-t0 + t1 + t2 - t3) * k::INV_RI;
    float la2 = (-t0 + t1 - t2 + t3) * k::A_RMOI;

    // l2a = rot(cos(t), sin(t)) -> [[c,-s,0],[s,c,0],[0,0,1]]
    float aa0 = c * la0 - s * la1;
    float aa1 = s * la0 + c * la1;

    o[0] = v0; o[1] = v1; o[2] = v2;
    o[3] = aa0; o[4] = aa1; o[5] = la2;
}

// Max memory-level parallelism, zero LDS, zero barriers:
//   one thread = 8 consecutive elements = 12 float4 (192 B),
//   all 12 loads issued as an independent cluster (12 KB in flight per wave),
//   all 8 elements computed in registers, 12 float4 stores.
// __launch_bounds__(256,4): 128-VGPR budget so the allocator doesn't sink
// the load cluster to save registers (R4's VGPR=28 showed exactly that).
__global__ __launch_bounds__(256, 4) void mecanum_ilp_kernel(
    const float4* __restrict__ in4,
    const float* __restrict__ cd,
    float4* __restrict__ out4,
    int n_groups) {
    int i = blockIdx.x * blockDim.x + threadIdx.x;
    if (i >= n_groups) return;

    const int base = i * 12;

    // ---- 12 independent loads, clustered ----
    float4 v[12];
#pragma unroll
    for (int j = 0; j < 12; ++j) v[j] = in4[base + j];

    // batch-uniform motor duty: CD2MD @ control_duty (uniform address ->
    // scalar loads, L2-broadcast, effectively free)
    float u0 = cd[0], u1 = cd[1], u2 = cd[2];
    const float m0 = u0 - u1 - u2;
    const float m1 = u0 + u1 + u2;
    const float m2 = u0 + u1 - u2;
    const float m3 = u0 - u1 + u2;

    float r[48];
#pragma unroll
    for (int j = 0; j < 12; ++j) {
        r[4 * j + 0] = v[j].x;
        r[4 * j + 1] = v[j].y;
        r[4 * j + 2] = v[j].z;
        r[4 * j + 3] = v[j].w;
    }

    // ---- 8 elements, in-place ----
#pragma unroll
    for (int e = 0; e < 8; ++e) {
        float st[6], o[6];
#pragma unroll
        for (int q = 0; q < 6; ++q) st[q] = r[6 * e + q];
        mecanum_elem(st, m0, m1, m2, m3, o);
#pragma unroll
        for (int q = 0; q < 6; ++q) r[6 * e + q] = o[q];
    }

    // ---- 12 stores ----
#pragma unroll
    for (int j = 0; j < 12; ++j)
        out4[base + j] = make_float4(r[4 * j + 0], r[4 * j + 1],
                                     r[4 * j + 2], r[4 * j + 3]);
}

// Scalar tail for n % 8 != 0 (defensive; BATCH=4M is divisible).
__global__ void mecanum_tail_kernel(const float* __restrict__ state,
                                    const float* __restrict__ cd,
                                    float* __restrict__ out,
                                    int start, int n) {
    int i = start + blockIdx.x * blockDim.x + threadIdx.x;
    if (i >= n) return;
    float u0 = cd[0], u1 = cd[1], u2 = cd[2];
    float m0 = u0 - u1 - u2;
    float m1 = u0 + u1 + u2;
    float m2 = u0 + u1 - u2;
    float m3 = u0 - u1 + u2;
    float st[6], o[6];
#pragma unroll
    for (int j = 0; j < 6; ++j) st[j] = state[6 * i + j];
    mecanum_elem(st, m0, m1, m2, m3, o);
#pragma unroll
    for (int j = 0; j < 6; ++j) out[6 * i + j] = o[j];
}

extern "C" void kernel_launch(void* const* d_in, const int* in_sizes, int n_in,
                              void* d_out, int out_size, void* d_ws, size_t ws_size,
                              hipStream_t stream) {
    // inputs: d_in[0] = t (1, unused), d_in[1] = state (BATCH*6), d_in[2] = control_duty (3)
    const float* state = (const float*)d_in[1];
    const float* cd    = (const float*)d_in[2];
    float* out         = (float*)d_out;

    int n = in_sizes[1] / 6;        // batch size
    int n_groups = n / 8;           // 8 elements (12 float4) per thread

    if (n_groups > 0) {
        int grid = (n_groups + 255) / 256;
        mecanum_ilp_kernel<<<grid, 256, 0, stream>>>(
            (const float4*)state, cd, (float4*)out, n_groups);
    }
    int done = n_groups * 8;
    if (done < n) {
        mecanum_tail_kernel<<<1, 64, 0, stream>>>(state, cd, out, done, n);
    }
}